// Round 3
// baseline (52.441 us; speedup 1.0000x reference)
//
#include <hip/hip_runtime.h>

#define N_ROIS 2048
#define N_CLSX 21
#define N_CLS_OUT 20
#define SCORE_T 0.3f
#define NMS_T 0.3f
#define DEDUP_T 0.3f
#define NVMAX 512
#define NWMAX (NVMAX / 64)
#define ASEG (N_CLS_OUT * N_ROIS)   // 40960 floats per ws array

// ============================ K1: decode all (roi, cls) ====================
#define RPB 64     // rois per block
#define NT1 256

__global__ __launch_bounds__(NT1) void decode_kernel(
    const float* __restrict__ rois,      // (2048,5)
    const float* __restrict__ cls_prob,  // (2048,21)
    const float* __restrict__ bbox_pred, // (2048,84)
    const float* __restrict__ im_info,   // (3,)
    float* __restrict__ ws)              // 5 arrays of [20][2048]
{
    __shared__ float lsc[RPB * 21];       // stride 21 (gcd(21,32)=1, ok)
    __shared__ float lbb[RPB * 85];       // pad 84->85 to avoid 8-way conflicts
    __shared__ float lroi[RPB * 5];

    const int tid = threadIdx.x;
    const int roi0 = blockIdx.x * RPB;

    for (int t = tid; t < RPB * 21; t += NT1) lsc[t] = cls_prob[roi0 * 21 + t];
    for (int t = tid; t < RPB * 84; t += NT1) {
        int r = t / 84, c = t - r * 84;
        lbb[r * 85 + c] = bbox_pred[roi0 * 84 + t];
    }
    for (int t = tid; t < RPB * 5; t += NT1) lroi[t] = rois[roi0 * 5 + t];
    __syncthreads();

    const float W = im_info[1], H = im_info[0];
    float* dx1 = ws;
    float* dy1 = ws + ASEG;
    float* dx2 = ws + 2 * ASEG;
    float* dy2 = ws + 3 * ASEG;
    float* dsc = ws + 4 * ASEG;

    for (int t = tid; t < RPB * N_CLS_OUT; t += NT1) {
        int cseg = t >> 6;          // 0..19  (class cseg+1)
        int rl = t & 63;
        int cls = cseg + 1;
        float x1 = lroi[rl * 5 + 1], y1 = lroi[rl * 5 + 2];
        float x2 = lroi[rl * 5 + 3], y2 = lroi[rl * 5 + 4];
        float w = x2 - x1 + 1.0f, h = y2 - y1 + 1.0f;
        float cx = x1 + 0.5f * w, cy = y1 + 0.5f * h;
        const float* d = &lbb[rl * 85 + cls * 4];
        float dx = d[0] * 0.1f, dy = d[1] * 0.1f;
        float dw = d[2] * 0.2f, dh = d[3] * 0.2f;
        float pcx = dx * w + cx, pcy = dy * h + cy;
        float pw = expf(dw) * w, ph = expf(dh) * h;
        int o = cseg * N_ROIS + roi0 + rl;   // 64 consecutive per wave: coalesced
        dx1[o] = fminf(fmaxf(pcx - 0.5f * pw, 0.0f), W - 1.0f);
        dy1[o] = fminf(fmaxf(pcy - 0.5f * ph, 0.0f), H - 1.0f);
        dx2[o] = fminf(fmaxf(pcx + 0.5f * pw, 0.0f), W - 1.0f);
        dy2[o] = fminf(fmaxf(pcy + 0.5f * ph, 0.0f), H - 1.0f);
        dsc[o] = lsc[rl * 21 + cls];
    }
}

// ============================ K2: per-class NMS + write ====================
#define NT2 256

__global__ __launch_bounds__(NT2) void nms_kernel(
    const float* __restrict__ ws,        // from K1
    const float* __restrict__ gt_boxes,  // (50,5)
    const int*   __restrict__ num_boxes,
    float* __restrict__ out)             // (20,2048,5)
{
    __shared__ float lsc2[N_ROIS];
    __shared__ float vsc[N_ROIS];
    __shared__ int   vidx[N_ROIS];
    __shared__ float sbx1[N_ROIS], sby1[N_ROIS], sbx2[N_ROIS], sby2[N_ROIS];
    __shared__ float ssc[N_ROIS];
    __shared__ unsigned long long supmat[NVMAX * NWMAX];
    __shared__ unsigned long long kwords[32];
    __shared__ unsigned char keepb[N_ROIS];
    __shared__ float sgt[50 * 4];
    __shared__ int nvalid;

    const int tid = threadIdx.x;
    const int cseg = blockIdx.x;        // 0..19
    const int cbase = cseg * N_ROIS;
    const int ng = *num_boxes;

    const float* dx1 = ws;
    const float* dy1 = ws + ASEG;
    const float* dx2 = ws + 2 * ASEG;
    const float* dy2 = ws + 3 * ASEG;
    const float* dsc = ws + 4 * ASEG;

    // coalesced score load + gt staging
    for (int t = tid; t < N_ROIS; t += NT2) lsc2[t] = dsc[cbase + t];
    for (int t = tid; t < ng * 4; t += NT2)
        sgt[t] = gt_boxes[(t >> 2) * 5 + (t & 3)];
    __syncthreads();

    // single-wave ordered compaction (roi-ascending preserved)
    if (tid < 64) {
        int base = 0;
        for (int chunk = 0; chunk < N_ROIS / 64; ++chunk) {
            int i = (chunk << 6) + tid;
            float sc = lsc2[i];
            bool valid = sc > SCORE_T;
            unsigned long long m = __ballot(valid);
            int pre = __popcll(m & ((1ULL << tid) - 1ULL));
            if (valid) { vidx[base + pre] = i; vsc[base + pre] = sc; }
            base += __popcll(m);
        }
        if (tid == 0) nvalid = base;
    }
    __syncthreads();
    const int nv = nvalid;

    // rank by (-score, roi idx asc) + gather decoded box into sorted slot
    for (int v = tid; v < nv; v += NT2) {
        float sc = vsc[v];
        int r = 0;
        for (int u = 0; u < nv; ++u) {
            float su = vsc[u];
            r += (su > sc) || (su == sc && u < v);   // vidx ascending => u<v
        }
        int idx = cbase + vidx[v];
        sbx1[r] = dx1[idx]; sby1[r] = dy1[idx];
        sbx2[r] = dx2[idx]; sby2[r] = dy2[idx];
        ssc[r]  = sc;
        keepb[r] = 1;
    }
    __syncthreads();

    const int NW = (nv + 63) >> 6;

    if (nv <= NVMAX) {
        // suppression bit-matrix
        const int wid = tid >> 6, lane = tid & 63;
        const int nwaves = NT2 / 64;
        for (int task = wid; task < nv * NW; task += nwaves) {
            int i = task / NW;
            int w = task - i * NW;
            float ax1 = sbx1[i], ay1 = sby1[i], ax2 = sbx2[i], ay2 = sby2[i];
            float aarea = (ax2 - ax1) * (ay2 - ay1);
            int j = (w << 6) + lane;
            bool bit = false;
            if (j < nv && j > i) {
                float ix1 = fmaxf(ax1, sbx1[j]);
                float iy1 = fmaxf(ay1, sby1[j]);
                float ix2 = fminf(ax2, sbx2[j]);
                float iy2 = fminf(ay2, sby2[j]);
                float iw = fmaxf(ix2 - ix1, 0.0f);
                float ih = fmaxf(iy2 - iy1, 0.0f);
                float inter = iw * ih;
                float barea = (sbx2[j] - sbx1[j]) * (sby2[j] - sby1[j]);
                float iou = inter / (aarea + barea - inter + 1e-6f);
                bit = iou > NMS_T;
            }
            unsigned long long word = __ballot(bit);
            if (lane == 0) supmat[task] = word;
        }
        __syncthreads();

        // greedy reduction on one wave (prefetchable row loads)
        if (tid < 64) {
            int lane = tid;
            int rem = nv - (lane << 6);
            unsigned long long kw =
                (lane < NW) ? ((rem >= 64) ? ~0ULL : ((1ULL << rem) - 1ULL))
                            : 0ULL;
            for (int i = 0; i < nv; ++i) {
                unsigned long long s =
                    (lane < NW) ? supmat[i * NW + lane] : 0ULL;  // independent
                unsigned long long kwi = __shfl(kw, i >> 6);     // dependent
                if ((kwi >> (i & 63)) & 1ULL) kw &= ~s;
            }
            if (lane < 32) kwords[lane] = kw;
        }
        __syncthreads();
    } else {
        // fallback: barrier-per-row greedy NMS
        for (int i = 0; i < nv; ++i) {
            __syncthreads();
            if (keepb[i]) {
                float ax1 = sbx1[i], ay1 = sby1[i], ax2 = sbx2[i], ay2 = sby2[i];
                float aarea = (ax2 - ax1) * (ay2 - ay1);
                for (int j = i + 1 + tid; j < nv; j += NT2) {
                    if (keepb[j]) {
                        float ix1 = fmaxf(ax1, sbx1[j]);
                        float iy1 = fmaxf(ay1, sby1[j]);
                        float ix2 = fminf(ax2, sbx2[j]);
                        float iy2 = fminf(ay2, sby2[j]);
                        float iw = fmaxf(ix2 - ix1, 0.0f);
                        float ih = fmaxf(iy2 - iy1, 0.0f);
                        float inter = iw * ih;
                        float barea = (sbx2[j] - sbx1[j]) * (sby2[j] - sby1[j]);
                        float iou = inter / (aarea + barea - inter + 1e-6f);
                        if (iou > NMS_T) keepb[j] = 0;
                    }
                }
            }
        }
        __syncthreads();
    }

    // GT dedup; finalize keepb
    for (int v = tid; v < nv; v += NT2) {
        bool kept = (nv <= NVMAX)
                        ? (bool)((kwords[v >> 6] >> (v & 63)) & 1ULL)
                        : (bool)keepb[v];
        bool dup = false;
        if (kept) {
            float ax1 = sbx1[v], ay1 = sby1[v], ax2 = sbx2[v], ay2 = sby2[v];
            float aarea = (ax2 - ax1) * (ay2 - ay1);
            for (int g = 0; g < ng; ++g) {
                float gx1 = sgt[g * 4 + 0], gy1 = sgt[g * 4 + 1];
                float gx2 = sgt[g * 4 + 2], gy2 = sgt[g * 4 + 3];
                float garea = (gx2 - gx1) * (gy2 - gy1);
                float ix1 = fmaxf(ax1, gx1);
                float iy1 = fmaxf(ay1, gy1);
                float ix2 = fminf(ax2, gx2);
                float iy2 = fminf(ay2, gy2);
                float iw = fmaxf(ix2 - ix1, 0.0f);
                float ih = fmaxf(iy2 - iy1, 0.0f);
                float inter = iw * ih;
                float iou = inter / (aarea + garea - inter + 1e-6f);
                if (iou > DEDUP_T) { dup = true; break; }
            }
        }
        keepb[v] = (kept && !dup) ? 1 : 0;
    }
    __syncthreads();

    // fully coalesced output write
    float* o = out + (size_t)cseg * N_ROIS * 5;
    for (int t = tid; t < N_ROIS * 5; t += NT2) {
        int j = t / 5, comp = t - 5 * j;
        bool m = (j < nv) && (keepb[j] != 0);
        float val;
        switch (comp) {
            case 0: val = sbx1[j]; break;
            case 1: val = sby1[j]; break;
            case 2: val = sbx2[j]; break;
            case 3: val = sby2[j]; break;
            default: val = ssc[j]; break;
        }
        o[t] = m ? val : 0.0f;
    }
}

extern "C" void kernel_launch(void* const* d_in, const int* in_sizes, int n_in,
                              void* d_out, int out_size, void* d_ws, size_t ws_size,
                              hipStream_t stream) {
    const float* rois      = (const float*)d_in[0];
    const float* cls_prob  = (const float*)d_in[1];
    const float* bbox_pred = (const float*)d_in[2];
    const float* im_info   = (const float*)d_in[3];
    const float* gt        = (const float*)d_in[4];
    const int*   nb        = (const int*)d_in[5];
    float* out = (float*)d_out;
    float* ws  = (float*)d_ws;

    decode_kernel<<<dim3(N_ROIS / RPB), dim3(NT1), 0, stream>>>(
        rois, cls_prob, bbox_pred, im_info, ws);
    nms_kernel<<<dim3(N_CLS_OUT), dim3(NT2), 0, stream>>>(
        ws, gt, nb, out);
}

// Round 4
// 39.800 us; speedup vs baseline: 1.3176x; 1.3176x over previous
//
#include <hip/hip_runtime.h>

#define N_ROIS 2048
#define N_CLSX 21
#define N_CLS_OUT 20
#define SCORE_T 0.3f
#define NMS_T 0.3f
#define DEDUP_T 0.3f
#define NT 256
#define NWAVES (NT / 64)
#define CPW (N_ROIS / 64 / NWAVES)   // 8 chunks of 64 rois per wave
#define NVMAX 512
#define NWMAX (NVMAX / 64)           // 8 keep-mask words

__global__ __launch_bounds__(NT) void detect_kernel(
    const float* __restrict__ rois,      // (2048,5)
    const float* __restrict__ cls_prob,  // (2048,21)
    const float* __restrict__ bbox_pred, // (2048,84)
    const float* __restrict__ im_info,   // (3,)
    const float* __restrict__ gt_boxes,  // (50,5)
    const int*   __restrict__ num_boxes,
    float* __restrict__ out)             // (20,2048,5)
{
    __shared__ float lsc[N_ROIS];                     // this class's scores
    __shared__ float vsc[N_ROIS];                     // compacted scores
    __shared__ int   vidx[N_ROIS];                    // compacted roi idx
    __shared__ float4 sbox[N_ROIS];                   // sorted decoded boxes
    __shared__ float  ssc[N_ROIS];                    // sorted scores
    __shared__ unsigned long long supmat[NVMAX * NWMAX]; // row-stride NWMAX
    __shared__ unsigned char keepb[N_ROIS];
    __shared__ float4 sgt[64];
    __shared__ int wbase[NWAVES];

    const int tid = threadIdx.x;
    const int wid = tid >> 6, lane = tid & 63;
    const int cls = blockIdx.x + 1;
    const int ng = *num_boxes;

    // ---- stage scores (strided; L2-resident after first block) + gt boxes
    for (int t = tid; t < N_ROIS; t += NT) lsc[t] = cls_prob[t * N_CLSX + cls];
    for (int g = tid; g < ng; g += NT)
        sgt[g] = make_float4(gt_boxes[g * 5 + 0], gt_boxes[g * 5 + 1],
                             gt_boxes[g * 5 + 2], gt_boxes[g * 5 + 3]);
    __syncthreads();

    // ---- compaction pass 1: per-wave valid masks + count (chain length 8)
    unsigned long long masks[CPW];
    int mycnt = 0;
    #pragma unroll
    for (int c = 0; c < CPW; ++c) {
        int i = ((wid * CPW + c) << 6) + lane;
        masks[c] = __ballot(lsc[i] > SCORE_T);
        mycnt += __popcll(masks[c]);
    }
    if (lane == 0) wbase[wid] = mycnt;
    __syncthreads();
    int base = 0;
    for (int w = 0; w < wid; ++w) base += wbase[w];
    int nvtot = 0;
    for (int w = 0; w < NWAVES; ++w) nvtot += wbase[w];
    const int nv = nvtot;

    // ---- compaction pass 2: ordered scatter (roi-ascending preserved)
    #pragma unroll
    for (int c = 0; c < CPW; ++c) {
        int i = ((wid * CPW + c) << 6) + lane;
        unsigned long long m = masks[c];
        if ((m >> lane) & 1ULL) {
            int pre = __popcll(m & ((1ULL << lane) - 1ULL));
            vidx[base + pre] = i;
            vsc[base + pre]  = lsc[i];
        }
        base += __popcll(m);
    }
    __syncthreads();

    // ---- rank by (-score, roi asc) + decode ONLY valid boxes, scatter sorted
    const float W = im_info[1], H = im_info[0];
    for (int v = tid; v < nv; v += NT) {
        float sc = vsc[v];
        int r = 0;
        for (int u = 0; u < nv; ++u) {
            float su = vsc[u];
            r += (su > sc) || (su == sc && u < v);
        }
        int idx = vidx[v];
        float x1 = rois[idx * 5 + 1], y1 = rois[idx * 5 + 2];
        float x2 = rois[idx * 5 + 3], y2 = rois[idx * 5 + 4];
        float w = x2 - x1 + 1.0f, h = y2 - y1 + 1.0f;
        float cx = x1 + 0.5f * w, cy = y1 + 0.5f * h;
        const float* d = &bbox_pred[idx * 84 + cls * 4];
        float dx = d[0] * 0.1f, dy = d[1] * 0.1f;
        float dw = d[2] * 0.2f, dh = d[3] * 0.2f;
        float pcx = dx * w + cx, pcy = dy * h + cy;
        float pw = expf(dw) * w, ph = expf(dh) * h;
        float4 b;
        b.x = fminf(fmaxf(pcx - 0.5f * pw, 0.0f), W - 1.0f);
        b.y = fminf(fmaxf(pcy - 0.5f * ph, 0.0f), H - 1.0f);
        b.z = fminf(fmaxf(pcx + 0.5f * pw, 0.0f), W - 1.0f);
        b.w = fminf(fmaxf(pcy + 0.5f * ph, 0.0f), H - 1.0f);
        sbox[r] = b;
        ssc[r]  = sc;
        keepb[r] = 1;
    }
    __syncthreads();

    auto dedup_test = [&](float4 a) -> bool {
        float aarea = (a.z - a.x) * (a.w - a.y);
        for (int g = 0; g < ng; ++g) {
            float4 gb = sgt[g];
            float ix1 = fmaxf(a.x, gb.x), iy1 = fmaxf(a.y, gb.y);
            float ix2 = fminf(a.z, gb.z), iy2 = fminf(a.w, gb.w);
            float iw = fmaxf(ix2 - ix1, 0.0f), ih = fmaxf(iy2 - iy1, 0.0f);
            float inter = iw * ih;
            float garea = (gb.z - gb.x) * (gb.w - gb.y);
            if (inter / (aarea + garea - inter + 1e-6f) > DEDUP_T) return true;
        }
        return false;
    };

    const int NW = (nv + 63) >> 6;

    if (nv <= NVMAX) {
        // ---- suppression bit-matrix (4 waves, off critical path)
        for (int task = wid; task < nv * NW; task += NWAVES) {
            int i = task / NW;
            int w = task - i * NW;
            float4 a = sbox[i];
            float aarea = (a.z - a.x) * (a.w - a.y);
            int j = (w << 6) + lane;
            bool bit = false;
            if (j < nv && j > i) {
                float4 bb = sbox[j];
                float ix1 = fmaxf(a.x, bb.x), iy1 = fmaxf(a.y, bb.y);
                float ix2 = fminf(a.z, bb.z), iy2 = fminf(a.w, bb.w);
                float iw = fmaxf(ix2 - ix1, 0.0f), ih = fmaxf(iy2 - iy1, 0.0f);
                float inter = iw * ih;
                float barea = (bb.z - bb.x) * (bb.w - bb.y);
                bit = inter / (aarea + barea - inter + 1e-6f) > NMS_T;
            }
            unsigned long long wd = __ballot(bit);
            if (lane == 0) supmat[i * NWMAX + w] = wd;
        }
        __syncthreads();

        // ---- greedy reduction: register keep-mask, no shfl in the loop.
        // All threads run it redundantly (wave-uniform); unwritten supmat
        // words w>=NW only AND into kw words that are already 0.
        #define INITKW(W_) ((nv > (W_)*64) \
            ? ((nv - (W_)*64 >= 64) ? ~0ULL : ((1ULL << (nv - (W_)*64)) - 1ULL)) \
            : 0ULL)
        unsigned long long kw0 = INITKW(0), kw1 = INITKW(1), kw2 = INITKW(2),
                           kw3 = INITKW(3), kw4 = INITKW(4), kw5 = INITKW(5),
                           kw6 = INITKW(6), kw7 = INITKW(7);
        #define PROC_WORD(KWW, WB)                                            \
        {                                                                     \
            int lim = nv - (WB); lim = lim > 64 ? 64 : lim;                   \
            for (int b = 0; b < lim; ++b) {                                   \
                if ((KWW >> b) & 1ULL) {                                      \
                    const unsigned long long* row = &supmat[((WB) + b) * NWMAX]; \
                    kw0 &= ~row[0]; kw1 &= ~row[1];                           \
                    kw2 &= ~row[2]; kw3 &= ~row[3];                           \
                    kw4 &= ~row[4]; kw5 &= ~row[5];                           \
                    kw6 &= ~row[6]; kw7 &= ~row[7];                           \
                }                                                             \
            }                                                                 \
        }
        PROC_WORD(kw0, 0);
        if (nv > 64)  PROC_WORD(kw1, 64);
        if (nv > 128) PROC_WORD(kw2, 128);
        if (nv > 192) PROC_WORD(kw3, 192);
        if (nv > 256) PROC_WORD(kw4, 256);
        if (nv > 320) PROC_WORD(kw5, 320);
        if (nv > 384) PROC_WORD(kw6, 384);
        if (nv > 448) PROC_WORD(kw7, 448);

        // ---- per-box kept bit + GT dedup, write keepb
        for (int v = tid; v < nv; v += NT) {
            int wsel = v >> 6;
            unsigned long long myw =
                wsel == 0 ? kw0 : wsel == 1 ? kw1 : wsel == 2 ? kw2 :
                wsel == 3 ? kw3 : wsel == 4 ? kw4 : wsel == 5 ? kw5 :
                wsel == 6 ? kw6 : kw7;
            bool kept = (myw >> (v & 63)) & 1ULL;
            if (kept) kept = !dedup_test(sbox[v]);
            keepb[v] = kept ? 1 : 0;
        }
        __syncthreads();
    } else {
        // ---- fallback: barrier-per-row greedy NMS (correctness-only path)
        for (int i = 0; i < nv; ++i) {
            __syncthreads();
            if (keepb[i]) {
                float4 a = sbox[i];
                float aarea = (a.z - a.x) * (a.w - a.y);
                for (int j = i + 1 + tid; j < nv; j += NT) {
                    if (keepb[j]) {
                        float4 bb = sbox[j];
                        float ix1 = fmaxf(a.x, bb.x), iy1 = fmaxf(a.y, bb.y);
                        float ix2 = fminf(a.z, bb.z), iy2 = fminf(a.w, bb.w);
                        float iw = fmaxf(ix2 - ix1, 0.0f), ih = fmaxf(iy2 - iy1, 0.0f);
                        float inter = iw * ih;
                        float barea = (bb.z - bb.x) * (bb.w - bb.y);
                        if (inter / (aarea + barea - inter + 1e-6f) > NMS_T)
                            keepb[j] = 0;
                    }
                }
            }
        }
        __syncthreads();
        for (int v = tid; v < nv; v += NT) {
            bool kept = keepb[v] != 0;
            if (kept) kept = !dedup_test(sbox[v]);
            keepb[v] = kept ? 1 : 0;
        }
        __syncthreads();
    }

    // ---- coalesced output write
    float* o = out + (size_t)blockIdx.x * N_ROIS * 5;
    for (int t = tid; t < N_ROIS * 5; t += NT) {
        int j = t / 5, comp = t - 5 * j;
        float val = 0.0f;
        if (j < nv && keepb[j]) {
            float4 b = sbox[j];
            val = comp == 0 ? b.x : comp == 1 ? b.y : comp == 2 ? b.z :
                  comp == 3 ? b.w : ssc[j];
        }
        o[t] = val;
    }
}

extern "C" void kernel_launch(void* const* d_in, const int* in_sizes, int n_in,
                              void* d_out, int out_size, void* d_ws, size_t ws_size,
                              hipStream_t stream) {
    const float* rois      = (const float*)d_in[0];
    const float* cls_prob  = (const float*)d_in[1];
    const float* bbox_pred = (const float*)d_in[2];
    const float* im_info   = (const float*)d_in[3];
    const float* gt        = (const float*)d_in[4];
    const int*   nb        = (const int*)d_in[5];
    float* out = (float*)d_out;

    detect_kernel<<<dim3(N_CLS_OUT), dim3(NT), 0, stream>>>(
        rois, cls_prob, bbox_pred, im_info, gt, nb, out);
}